// Round 8
// baseline (28699.399 us; speedup 1.0000x reference)
//
#include <hip/hip_runtime.h>

typedef _Float16 f16;
typedef _Float16 h2 __attribute__((ext_vector_type(2)));
typedef float f32x2 __attribute__((ext_vector_type(2)));

#define NBATCH 64
#define TSTEPS 1024
#define NH 256
#define FSTR 44

#define OFF_FEAT 0ull
#define OFF_XZ   11534336ull      // 65536*44*4
#define OFF_H    145752064ull     // + 65536*1024*2
#define OFF_UPK  179306496ull     // + 65536*256*2 ; 3 layers * 256KB fp8
// total ws use: 180,092,928 bytes

// 32 k-chunks of U in fp8: chunk q, col c = uint2 holding k-rows 8q..8q+7 of col c.
// QLDS chunks live in LDS (one-time copy); the remaining QREG chunks live in
// per-thread REGISTERS (step-invariant, 56 VGPRs) -> zero in-loop weight traffic.
#define QLDS 18
#define QALL 32
#define QREG (QALL - QLDS)       // 14
// LDS: w-slice 18*1024*8 = 147456, hstore 1024, arr 4096 -> 152576 B
#define SMEM_SCAN8 (QLDS * 1024 * 8 + 1024 + 4096)

__device__ __forceinline__ float sigmf(float z) {
  return 1.f / (1.f + __expf(-z));
}

__device__ __forceinline__ float wave_sum64(float v) {
#pragma unroll
  for (int off = 32; off; off >>= 1) v += __shfl_xor(v, off);
  return v;
}

// decode 4 fp8 (one dword, k-values r..r+3) and mac against h[r..r+3]
__device__ __forceinline__ void fp8x4_mac(unsigned w, float4 hv,
                                          float& a0, float& a1) {
  f32x2 lo = __builtin_amdgcn_cvt_pk_f32_fp8(w, false);  // bytes 0,1
  f32x2 hi = __builtin_amdgcn_cvt_pk_f32_fp8(w, true);   // bytes 2,3
  a0 = fmaf(lo.x, hv.x, a0);
  a1 = fmaf(lo.y, hv.y, a1);
  a0 = fmaf(hi.x, hv.z, a0);
  a1 = fmaf(hi.y, hv.w, a1);
}

// ---- U conversion: f32 [256][1024] -> fp8 chunks uint2[32][1024] ----
// out[q*1024+c]: .x = fp8(U[8q..8q+3][c]) bytes 0..3, .y = fp8(U[8q+4..8q+7][c])
__global__ __launch_bounds__(256) void cvt_u_fp8(const float* __restrict__ U,
                                                 uint2* __restrict__ dst) {
  int id = blockIdx.x * 256 + threadIdx.x;   // < 32768
  int q = id >> 10, c = id & 1023;
  unsigned vx = 0, vy = 0;
  vx = __builtin_amdgcn_cvt_pk_fp8_f32(U[(8 * q + 0) * 1024 + c],
                                       U[(8 * q + 1) * 1024 + c], vx, false);
  vx = __builtin_amdgcn_cvt_pk_fp8_f32(U[(8 * q + 2) * 1024 + c],
                                       U[(8 * q + 3) * 1024 + c], vx, true);
  vy = __builtin_amdgcn_cvt_pk_fp8_f32(U[(8 * q + 4) * 1024 + c],
                                       U[(8 * q + 5) * 1024 + c], vy, false);
  vy = __builtin_amdgcn_cvt_pk_fp8_f32(U[(8 * q + 6) * 1024 + c],
                                       U[(8 * q + 7) * 1024 + c], vy, true);
  dst[id] = uint2{vx, vy};
}

// ---------------- embeddings -> feat [65536][44] (41 used) ----------------
__global__ __launch_bounds__(256) void embed_feat(
    const float* __restrict__ x,
    const float* __restrict__ pe_w1, const float* __restrict__ pe_b1,
    const float* __restrict__ pe_w2, const float* __restrict__ pe_b2,
    const float* __restrict__ te_w1, const float* __restrict__ te_b1,
    const float* __restrict__ te_w2, const float* __restrict__ te_b2,
    float* __restrict__ feat) {
  __shared__ float w[2548];
  const int tid = threadIdx.x;
  for (int i = tid; i < 595; i += 256) w[i] = te_w1[i];
  for (int i = tid; i < 17; i += 256) w[595 + i] = te_b1[i];
  for (int i = tid; i < 85; i += 256) w[612 + i] = te_w2[i];
  for (int i = tid; i < 5; i += 256) w[697 + i] = te_b2[i];
  for (int i = tid; i < 1539; i += 256) w[702 + i] = pe_w1[i];
  for (int i = tid; i < 27; i += 256) w[2241 + i] = pe_b1[i];
  for (int i = tid; i < 270; i += 256) w[2268 + i] = pe_w2[i];
  for (int i = tid; i < 10; i += 256) w[2538 + i] = pe_b2[i];
  __syncthreads();

  int row = blockIdx.x * 256 + tid;   // < 65536
  const float* xr = x + (size_t)row * 212;
  float* fr = feat + (size_t)row * FSTR;

  // team MLP 35 -> 17 -> 5
  {
    float h1[17];
#pragma unroll
    for (int h = 0; h < 17; ++h) h1[h] = w[595 + h];
    for (int k = 0; k < 35; ++k) {
      float xv = xr[k];
#pragma unroll
      for (int h = 0; h < 17; ++h) h1[h] += xv * w[k * 17 + h];
    }
#pragma unroll
    for (int h = 0; h < 17; ++h) h1[h] = fmaxf(h1[h], 0.f);
    float t2[5];
#pragma unroll
    for (int h = 0; h < 5; ++h) t2[h] = w[697 + h];
#pragma unroll
    for (int k = 0; k < 17; ++k) {
#pragma unroll
      for (int h = 0; h < 5; ++h) t2[h] += h1[k] * w[612 + k * 5 + h];
    }
#pragma unroll
    for (int h = 0; h < 5; ++h) fr[h] = fmaxf(t2[h], 0.f);
  }
  // player MLP 57 -> 27 -> 10, three slices s/a/bk
  for (int p = 0; p < 3; ++p) {
    const float* xp = xr + 35 + 57 * p;
    float h1[27];
#pragma unroll
    for (int h = 0; h < 27; ++h) h1[h] = w[2241 + h];
    for (int k = 0; k < 57; ++k) {
      float xv = xp[k];
#pragma unroll
      for (int h = 0; h < 27; ++h) h1[h] += xv * w[702 + k * 27 + h];
    }
#pragma unroll
    for (int h = 0; h < 27; ++h) h1[h] = fmaxf(h1[h], 0.f);
    float t2[10];
#pragma unroll
    for (int h = 0; h < 10; ++h) t2[h] = w[2538 + h];
#pragma unroll
    for (int k = 0; k < 27; ++k) {
#pragma unroll
      for (int h = 0; h < 10; ++h) t2[h] += h1[k] * w[2268 + k * 10 + h];
    }
#pragma unroll
    for (int h = 0; h < 10; ++h) fr[5 + 10 * p + h] = fmaxf(t2[h], 0.f);
  }
  // extra passthrough
#pragma unroll
  for (int e = 0; e < 6; ++e) fr[35 + e] = xr[206 + e];
}

// ---------------- xz1 = feat @ W1 + b  (K=41) -> f16 ----------------
__global__ __launch_bounds__(256) void gemm_feat(
    const float* __restrict__ feat, const float* __restrict__ W,
    const float* __restrict__ bias, f16* __restrict__ C) {
  __shared__ float Wl[41 * 256];
  __shared__ float fl[64 * FSTR];
  int m0 = blockIdx.x * 64, n0 = blockIdx.y * 256;
  int t = threadIdx.x;
  for (int r = 0; r < 41; ++r) Wl[r * 256 + t] = W[r * 1024 + n0 + t];
  for (int i = t; i < 64 * FSTR; i += 256) fl[i] = feat[(size_t)m0 * FSTR + i];
  __syncthreads();
  float bv = bias[n0 + t];
  for (int r = 0; r < 64; ++r) {
    float acc = bv;
#pragma unroll
    for (int k = 0; k < 41; ++k) acc += fl[r * FSTR + k] * Wl[k * 256 + t];
    C[(size_t)(m0 + r) * 1024 + n0 + t] = (f16)acc;
  }
}

// ---------------- xz = h_seq(f16) @ W(f32) + b -> f16   (K=256) ----------------
__global__ __launch_bounds__(256) void gemm_h(
    const f16* __restrict__ A, const float* __restrict__ B,
    const float* __restrict__ bias, f16* __restrict__ C) {
  __shared__ float As[32][72];
  __shared__ float Bs[32][64];
  int m0 = blockIdx.x * 64, n0 = blockIdx.y * 64;
  int t = threadIdx.x;
  int tx = t & 15, ty = t >> 4;
  float acc[4][4];
#pragma unroll
  for (int i = 0; i < 4; ++i)
#pragma unroll
    for (int j = 0; j < 4; ++j) acc[i][j] = 0.f;

  float bcol[4];
#pragma unroll
  for (int j = 0; j < 4; ++j) bcol[j] = bias[n0 + tx * 4 + j];

  for (int k0 = 0; k0 < 256; k0 += 32) {
    {
      int r = t >> 2, kq = (t & 3) * 8;
      const f16* ap = A + (size_t)(m0 + r) * 256 + k0 + kq;
      float4 raw = *(const float4*)ap;   // 8 halves
      const f16* hv = (const f16*)&raw;
#pragma unroll
      for (int q = 0; q < 8; ++q) As[kq + q][r] = (float)hv[q];
    }
    {
      int kr = t >> 3, nq = (t & 7) * 8;
      const float* bp = B + (size_t)(k0 + kr) * 1024 + n0 + nq;
      float4 b0 = *(const float4*)bp;
      float4 b1 = *(const float4*)(bp + 4);
      *(float4*)&Bs[kr][nq] = b0;
      *(float4*)&Bs[kr][nq + 4] = b1;
    }
    __syncthreads();
#pragma unroll
    for (int kk = 0; kk < 32; ++kk) {
      float4 av = *(const float4*)&As[kk][ty * 4];
      float4 bv = *(const float4*)&Bs[kk][tx * 4];
      const float* ap = (const float*)&av;
      const float* bp = (const float*)&bv;
#pragma unroll
      for (int i = 0; i < 4; ++i)
#pragma unroll
        for (int j = 0; j < 4; ++j) acc[i][j] += ap[i] * bp[j];
    }
    __syncthreads();
  }
#pragma unroll
  for (int i = 0; i < 4; ++i) {
    int row = m0 + ty * 4 + i;
    alignas(8) f16 ov[4];
#pragma unroll
    for (int j = 0; j < 4; ++j) ov[j] = (f16)(acc[i][j] + bcol[j]);
    *(uint2*)(C + (size_t)row * 1024 + n0 + tx * 4) = *(const uint2*)ov;
  }
}

// ---------------- recurrent scan: one workgroup per batch element ----------------
// 512 threads; thread t owns gate columns t (i/f) and t+512 (g/o).
// U fp8: 18 chunks in LDS, 14 chunks in NAMED per-thread registers (56 VGPRs,
// step-invariant -> zero in-loop weight VMEM; named vars avoid runtime indexing
// which would go to scratch). Phase 2 (gate math) runs on wave 0 only with 4
// c-components per lane -> both softmax reductions are intra-wave shuffles;
// 2 barriers per step instead of 3.
#define REGDECL(i) uint2 wr##i##a, wr##i##b;
#define REGLOAD(i)                                \
  wr##i##a = Wt[(i) * 1024 + t];                  \
  wr##i##b = Wt[(i) * 1024 + t + 512];
#define DOREG(i) {                                \
    float4 h0 = hst4[2 * (QLDS + (i))];           \
    float4 h1 = hst4[2 * (QLDS + (i)) + 1];       \
    fp8x4_mac(wr##i##a.x, h0, a0, a1);            \
    fp8x4_mac(wr##i##a.y, h1, a0, a1);            \
    fp8x4_mac(wr##i##b.x, h0, b0, b1);            \
    fp8x4_mac(wr##i##b.y, h1, b0, b1);            \
  }

__global__ __launch_bounds__(512) void lstm_scan_f8(
    const uint2* __restrict__ Wall,  // [32][1024] fp8 chunks, layer-specific
    const f16* __restrict__ xz,      // [64][1024][1024]
    f16* __restrict__ hseq) {        // [64][1024][256]
  extern __shared__ char smem[];
  uint2* wlds = (uint2*)smem;                               // 147456 B
  float* hstore = (float*)(smem + QLDS * 1024 * 8);         // 1024 B
  float* arr = (float*)(smem + QLDS * 1024 * 8 + 1024);     // 4096 B

  const int bid = blockIdx.x;
  const int t = threadIdx.x;
  const bool lowhalf = (t < 256);
  const uint2* Wt = Wall + QLDS * 1024;   // register-resident chunks
  const float4* hst4 = (const float4*)hstore;
  const float4* arr4 = (const float4*)arr;

  // load the register-resident W slice (one-time, step-invariant)
  REGDECL(0) REGDECL(1) REGDECL(2) REGDECL(3) REGDECL(4) REGDECL(5) REGDECL(6)
  REGDECL(7) REGDECL(8) REGDECL(9) REGDECL(10) REGDECL(11) REGDECL(12) REGDECL(13)
  REGLOAD(0) REGLOAD(1) REGLOAD(2) REGLOAD(3) REGLOAD(4) REGLOAD(5) REGLOAD(6)
  REGLOAD(7) REGLOAD(8) REGLOAD(9) REGLOAD(10) REGLOAD(11) REGLOAD(12) REGLOAD(13)

  // one-time copy of the LDS-resident W slice
  for (int i = t; i < QLDS * 1024; i += 512) wlds[i] = Wall[i];
  if (t < 256) hstore[t] = 0.f;
  // wave 0: 4 c-components per lane
  float c0 = 0.f, c1 = 0.f, c2 = 0.f, c3 = 0.f;
  __syncthreads();

#pragma unroll 1
  for (int step = 0; step < TSTEPS; ++step) {
    const f16* xzrow = xz + ((size_t)bid * TSTEPS + step) * 1024;
    float xza = (float)xzrow[t];
    float xzb = (float)xzrow[t + 512];

    float a0 = 0.f, a1 = 0.f, b0 = 0.f, b1 = 0.f;
#pragma unroll 4
    for (int q = 0; q < QLDS; ++q) {      // LDS-resident chunks
      uint2 wa = wlds[q * 1024 + t];
      uint2 wb = wlds[q * 1024 + t + 512];
      float4 h0 = hst4[2 * q];            // h[8q .. 8q+3] (broadcast)
      float4 h1 = hst4[2 * q + 1];        // h[8q+4 .. 8q+7]
      fp8x4_mac(wa.x, h0, a0, a1);
      fp8x4_mac(wa.y, h1, a0, a1);
      fp8x4_mac(wb.x, h0, b0, b1);
      fp8x4_mac(wb.y, h1, b0, b1);
    }
    // register-resident chunks (fully unrolled, compile-time indices only)
    DOREG(0) DOREG(1) DOREG(2) DOREG(3) DOREG(4) DOREG(5) DOREG(6)
    DOREG(7) DOREG(8) DOREG(9) DOREG(10) DOREG(11) DOREG(12) DOREG(13)

    float za = xza + a0 + a1;    // col t:      i (t<256) / f (t>=256)
    float zb = xzb + b0 + b1;    // col t+512:  g (t<256) / o (t>=256)

    float sa = sigmf(za);
    float ab = lowhalf ? __expf(zb) : sigmf(zb);
    // arr layout: [0..255]=sig(i), [256..511]=sig(f), [512..767]=exp(g),
    //             [768..1023]=sig(o)
    arr[t] = sa;
    arr[512 + t] = ab;
    __syncthreads();               // barrier A: arr visible to wave 0

    if (t < 64) {                  // phase 2: wave 0, lane l owns c[4l..4l+3]
      float4 iv = arr4[t];         // sig(i)
      float4 fv = arr4[64 + t];    // sig(f)
      float4 gv = arr4[128 + t];   // exp(g)
      float4 ov = arr4[192 + t];   // sig(o)
      float gs = wave_sum64(gv.x + gv.y + gv.z + gv.w);
      float ginv = 1.f / gs;
      c0 = fmaf(fv.x, c0, iv.x * gv.x * ginv);
      c1 = fmaf(fv.y, c1, iv.y * gv.y * ginv);
      c2 = fmaf(fv.z, c2, iv.z * gv.z * ginv);
      c3 = fmaf(fv.w, c3, iv.w * gv.w * ginv);
      float e0 = __expf(c0), e1 = __expf(c1), e2 = __expf(c2), e3 = __expf(c3);
      float cs = wave_sum64(e0 + e1 + e2 + e3);
      float cinv = 1.f / cs;
      float h0 = ov.x * e0 * cinv, h1 = ov.y * e1 * cinv;
      float h2v = ov.z * e2 * cinv, h3 = ov.w * e3 * cinv;
      ((float4*)hstore)[t] = float4{h0, h1, h2v, h3};
      alignas(8) f16 hv4[4] = {(f16)h0, (f16)h1, (f16)h2v, (f16)h3};
      *(uint2*)(hseq + ((size_t)bid * TSTEPS + step) * NH + 4 * t) =
          *(const uint2*)hv4;
    }
    __syncthreads();               // barrier B: hstore visible to all
  }
}

// ---------------- head: dense 256->100->40->2 + softmax ----------------
__global__ __launch_bounds__(128) void head_k(
    const f16* __restrict__ hseq,
    const float* __restrict__ d1w, const float* __restrict__ d1b,
    const float* __restrict__ d2w, const float* __restrict__ d2b,
    const float* __restrict__ d3w, const float* __restrict__ d3b,
    float* __restrict__ out) {
  __shared__ float hl[256], o1[100], o2[40];
  int b = blockIdx.x, t = threadIdx.x;
  const f16* hrow = hseq + ((size_t)b * TSTEPS + (TSTEPS - 1)) * NH;
  for (int i = t; i < 256; i += 128) hl[i] = (float)hrow[i];
  __syncthreads();
  if (t < 100) {
    float acc = d1b[t];
    for (int k = 0; k < 256; ++k) acc += hl[k] * d1w[k * 100 + t];
    o1[t] = fmaxf(acc, 0.f);
  }
  __syncthreads();
  if (t < 40) {
    float acc = d2b[t];
    for (int k = 0; k < 100; ++k) acc += o1[k] * d2w[k * 40 + t];
    o2[t] = fmaxf(acc, 0.f);
  }
  __syncthreads();
  if (t == 0) {
    float a0 = d3b[0], a1 = d3b[1];
    for (int k = 0; k < 40; ++k) {
      a0 += o2[k] * d3w[k * 2];
      a1 += o2[k] * d3w[k * 2 + 1];
    }
    float m = fmaxf(a0, a1);
    float e0 = __expf(a0 - m), e1 = __expf(a1 - m);
    float s = e0 + e1;
    out[b * 2] = e0 / s;
    out[b * 2 + 1] = e1 / s;
  }
}

extern "C" void kernel_launch(void* const* d_in, const int* in_sizes, int n_in,
                              void* d_out, int out_size, void* d_ws, size_t ws_size,
                              hipStream_t stream) {
  const float* x = (const float*)d_in[0];
  const float* pe_w1 = (const float*)d_in[1];
  const float* pe_b1 = (const float*)d_in[2];
  const float* pe_w2 = (const float*)d_in[3];
  const float* pe_b2 = (const float*)d_in[4];
  const float* te_w1 = (const float*)d_in[5];
  const float* te_b1 = (const float*)d_in[6];
  const float* te_w2 = (const float*)d_in[7];
  const float* te_b2 = (const float*)d_in[8];
  const float* W1 = (const float*)d_in[9];
  const float* U1 = (const float*)d_in[10];
  const float* bl1 = (const float*)d_in[11];
  const float* W2 = (const float*)d_in[12];
  const float* U2m = (const float*)d_in[13];
  const float* bl2 = (const float*)d_in[14];
  const float* W3 = (const float*)d_in[15];
  const float* U3 = (const float*)d_in[16];
  const float* bl3 = (const float*)d_in[17];
  const float* d1w = (const float*)d_in[18];
  const float* d1b = (const float*)d_in[19];
  const float* d2w = (const float*)d_in[20];
  const float* d2b = (const float*)d_in[21];
  const float* d3w = (const float*)d_in[22];
  const float* d3b = (const float*)d_in[23];
  float* out = (float*)d_out;

  char* ws = (char*)d_ws;
  float* feat = (float*)(ws + OFF_FEAT);
  f16* xzbuf = (f16*)(ws + OFF_XZ);
  f16* hseq = (f16*)(ws + OFF_H);
  uint2* upk = (uint2*)(ws + OFF_UPK);   // 3 layers x 32768 uint2

  hipFuncSetAttribute((const void*)lstm_scan_f8,
                      hipFuncAttributeMaxDynamicSharedMemorySize, SMEM_SCAN8);

  const float* Us[3] = {U1, U2m, U3};
  for (int l = 0; l < 3; ++l)
    cvt_u_fp8<<<128, 256, 0, stream>>>(Us[l], upk + (size_t)l * 32768);

  embed_feat<<<256, 256, 0, stream>>>(x, pe_w1, pe_b1, pe_w2, pe_b2,
                                      te_w1, te_b1, te_w2, te_b2, feat);
  gemm_feat<<<dim3(1024, 4), 256, 0, stream>>>(feat, W1, bl1, xzbuf);
  lstm_scan_f8<<<64, 512, SMEM_SCAN8, stream>>>(upk, xzbuf, hseq);

  gemm_h<<<dim3(1024, 16), 256, 0, stream>>>(hseq, W2, bl2, xzbuf);
  lstm_scan_f8<<<64, 512, SMEM_SCAN8, stream>>>(upk + 32768, xzbuf, hseq);

  gemm_h<<<dim3(1024, 16), 256, 0, stream>>>(hseq, W3, bl3, xzbuf);
  lstm_scan_f8<<<64, 512, SMEM_SCAN8, stream>>>(upk + 2 * 32768, xzbuf, hseq);

  head_k<<<64, 128, 0, stream>>>(hseq, d1w, d1b, d2w, d2b, d3w, d3b, out);
}

// Round 10
// 14467.105 us; speedup vs baseline: 1.9838x; 1.9838x over previous
//
#include <hip/hip_runtime.h>

typedef _Float16 f16;
typedef _Float16 h2 __attribute__((ext_vector_type(2)));
typedef float f32x2 __attribute__((ext_vector_type(2)));

#define NBATCH 64
#define TSTEPS 1024
#define NH 256
#define FSTR 44

#define OFF_FEAT 0ull
#define OFF_XZ   11534336ull      // 65536*44*4
#define OFF_H    145752064ull     // + 65536*1024*2
#define OFF_UPK  179306496ull     // + 65536*256*2 ; 3 layers * 256KB fp8
// total ws use: 180,092,928 bytes

// 32 k-chunks of U in fp8: chunk q, col c = uint2 holding k-rows 8q..8q+7 of col c.
// QLDS chunks live in LDS (one-time copy), the rest stream from L2 every step.
// QLDS=19: 155648 B weights + 5184 B state = 160832 B < 163840 B LDS cap.
#define QLDS 19
#define QALL 32
#define QSTR (QALL - QLDS)       // 13
// LDS: w-slice 19*1024*8 = 155648, hstore 1024, arr 4096, red 64 -> 160832 B
#define SMEM_SCAN8 (QLDS * 1024 * 8 + 1024 + 4096 + 64)

__device__ __forceinline__ float sigmf(float z) {
  return 1.f / (1.f + __expf(-z));
}

__device__ __forceinline__ float wave_sum64(float v) {
#pragma unroll
  for (int off = 32; off; off >>= 1) v += __shfl_xor(v, off);
  return v;
}

// decode 4 fp8 (one dword, k-values r..r+3) and mac against h[r..r+3].
// cvt_pk_f32_fp8 returns a packed f32x2; vector FMA lets clang emit
// v_pk_fma_f32 (2 MACs/inst) — 4 VALU per dword instead of 6.
__device__ __forceinline__ void fp8x4_mac2(unsigned w, float4 hv,
                                           f32x2& acc0, f32x2& acc1) {
  f32x2 lo = __builtin_amdgcn_cvt_pk_f32_fp8(w, false);  // bytes 0,1
  f32x2 hi = __builtin_amdgcn_cvt_pk_f32_fp8(w, true);   // bytes 2,3
  f32x2 h01; h01.x = hv.x; h01.y = hv.y;
  f32x2 h23; h23.x = hv.z; h23.y = hv.w;
  acc0 += lo * h01;
  acc1 += hi * h23;
}

// ---- U conversion: f32 [256][1024] -> fp8 chunks uint2[32][1024] ----
// out[q*1024+c]: .x = fp8(U[8q..8q+3][c]) bytes 0..3, .y = fp8(U[8q+4..8q+7][c])
__global__ __launch_bounds__(256) void cvt_u_fp8(const float* __restrict__ U,
                                                 uint2* __restrict__ dst) {
  int id = blockIdx.x * 256 + threadIdx.x;   // < 32768
  int q = id >> 10, c = id & 1023;
  unsigned vx = 0, vy = 0;
  vx = __builtin_amdgcn_cvt_pk_fp8_f32(U[(8 * q + 0) * 1024 + c],
                                       U[(8 * q + 1) * 1024 + c], vx, false);
  vx = __builtin_amdgcn_cvt_pk_fp8_f32(U[(8 * q + 2) * 1024 + c],
                                       U[(8 * q + 3) * 1024 + c], vx, true);
  vy = __builtin_amdgcn_cvt_pk_fp8_f32(U[(8 * q + 4) * 1024 + c],
                                       U[(8 * q + 5) * 1024 + c], vy, false);
  vy = __builtin_amdgcn_cvt_pk_fp8_f32(U[(8 * q + 6) * 1024 + c],
                                       U[(8 * q + 7) * 1024 + c], vy, true);
  dst[id] = uint2{vx, vy};
}

// ---------------- embeddings -> feat [65536][44] (41 used) ----------------
__global__ __launch_bounds__(256) void embed_feat(
    const float* __restrict__ x,
    const float* __restrict__ pe_w1, const float* __restrict__ pe_b1,
    const float* __restrict__ pe_w2, const float* __restrict__ pe_b2,
    const float* __restrict__ te_w1, const float* __restrict__ te_b1,
    const float* __restrict__ te_w2, const float* __restrict__ te_b2,
    float* __restrict__ feat) {
  __shared__ float w[2548];
  const int tid = threadIdx.x;
  for (int i = tid; i < 595; i += 256) w[i] = te_w1[i];
  for (int i = tid; i < 17; i += 256) w[595 + i] = te_b1[i];
  for (int i = tid; i < 85; i += 256) w[612 + i] = te_w2[i];
  for (int i = tid; i < 5; i += 256) w[697 + i] = te_b2[i];
  for (int i = tid; i < 1539; i += 256) w[702 + i] = pe_w1[i];
  for (int i = tid; i < 27; i += 256) w[2241 + i] = pe_b1[i];
  for (int i = tid; i < 270; i += 256) w[2268 + i] = pe_w2[i];
  for (int i = tid; i < 10; i += 256) w[2538 + i] = pe_b2[i];
  __syncthreads();

  int row = blockIdx.x * 256 + tid;   // < 65536
  const float* xr = x + (size_t)row * 212;
  float* fr = feat + (size_t)row * FSTR;

  // team MLP 35 -> 17 -> 5
  {
    float h1[17];
#pragma unroll
    for (int h = 0; h < 17; ++h) h1[h] = w[595 + h];
    for (int k = 0; k < 35; ++k) {
      float xv = xr[k];
#pragma unroll
      for (int h = 0; h < 17; ++h) h1[h] += xv * w[k * 17 + h];
    }
#pragma unroll
    for (int h = 0; h < 17; ++h) h1[h] = fmaxf(h1[h], 0.f);
    float t2[5];
#pragma unroll
    for (int h = 0; h < 5; ++h) t2[h] = w[697 + h];
#pragma unroll
    for (int k = 0; k < 17; ++k) {
#pragma unroll
      for (int h = 0; h < 5; ++h) t2[h] += h1[k] * w[612 + k * 5 + h];
    }
#pragma unroll
    for (int h = 0; h < 5; ++h) fr[h] = fmaxf(t2[h], 0.f);
  }
  // player MLP 57 -> 27 -> 10, three slices s/a/bk
  for (int p = 0; p < 3; ++p) {
    const float* xp = xr + 35 + 57 * p;
    float h1[27];
#pragma unroll
    for (int h = 0; h < 27; ++h) h1[h] = w[2241 + h];
    for (int k = 0; k < 57; ++k) {
      float xv = xp[k];
#pragma unroll
      for (int h = 0; h < 27; ++h) h1[h] += xv * w[702 + k * 27 + h];
    }
#pragma unroll
    for (int h = 0; h < 27; ++h) h1[h] = fmaxf(h1[h], 0.f);
    float t2[10];
#pragma unroll
    for (int h = 0; h < 10; ++h) t2[h] = w[2538 + h];
#pragma unroll
    for (int k = 0; k < 27; ++k) {
#pragma unroll
      for (int h = 0; h < 10; ++h) t2[h] += h1[k] * w[2268 + k * 10 + h];
    }
#pragma unroll
    for (int h = 0; h < 10; ++h) fr[5 + 10 * p + h] = fmaxf(t2[h], 0.f);
  }
  // extra passthrough
#pragma unroll
  for (int e = 0; e < 6; ++e) fr[35 + e] = xr[206 + e];
}

// ---------------- xz1 = feat @ W1 + b  (K=41) -> f16 ----------------
__global__ __launch_bounds__(256) void gemm_feat(
    const float* __restrict__ feat, const float* __restrict__ W,
    const float* __restrict__ bias, f16* __restrict__ C) {
  __shared__ float Wl[41 * 256];
  __shared__ float fl[64 * FSTR];
  int m0 = blockIdx.x * 64, n0 = blockIdx.y * 256;
  int t = threadIdx.x;
  for (int r = 0; r < 41; ++r) Wl[r * 256 + t] = W[r * 1024 + n0 + t];
  for (int i = t; i < 64 * FSTR; i += 256) fl[i] = feat[(size_t)m0 * FSTR + i];
  __syncthreads();
  float bv = bias[n0 + t];
  for (int r = 0; r < 64; ++r) {
    float acc = bv;
#pragma unroll
    for (int k = 0; k < 41; ++k) acc += fl[r * FSTR + k] * Wl[k * 256 + t];
    C[(size_t)(m0 + r) * 1024 + n0 + t] = (f16)acc;
  }
}

// ---------------- xz = h_seq(f16) @ W(f32) + b -> f16   (K=256) ----------------
__global__ __launch_bounds__(256) void gemm_h(
    const f16* __restrict__ A, const float* __restrict__ B,
    const float* __restrict__ bias, f16* __restrict__ C) {
  __shared__ float As[32][72];
  __shared__ float Bs[32][64];
  int m0 = blockIdx.x * 64, n0 = blockIdx.y * 64;
  int t = threadIdx.x;
  int tx = t & 15, ty = t >> 4;
  float acc[4][4];
#pragma unroll
  for (int i = 0; i < 4; ++i)
#pragma unroll
    for (int j = 0; j < 4; ++j) acc[i][j] = 0.f;

  float bcol[4];
#pragma unroll
  for (int j = 0; j < 4; ++j) bcol[j] = bias[n0 + tx * 4 + j];

  for (int k0 = 0; k0 < 256; k0 += 32) {
    {
      int r = t >> 2, kq = (t & 3) * 8;
      const f16* ap = A + (size_t)(m0 + r) * 256 + k0 + kq;
      float4 raw = *(const float4*)ap;   // 8 halves
      const f16* hv = (const f16*)&raw;
#pragma unroll
      for (int q = 0; q < 8; ++q) As[kq + q][r] = (float)hv[q];
    }
    {
      int kr = t >> 3, nq = (t & 7) * 8;
      const float* bp = B + (size_t)(k0 + kr) * 1024 + n0 + nq;
      float4 b0 = *(const float4*)bp;
      float4 b1 = *(const float4*)(bp + 4);
      *(float4*)&Bs[kr][nq] = b0;
      *(float4*)&Bs[kr][nq + 4] = b1;
    }
    __syncthreads();
#pragma unroll
    for (int kk = 0; kk < 32; ++kk) {
      float4 av = *(const float4*)&As[kk][ty * 4];
      float4 bv = *(const float4*)&Bs[kk][tx * 4];
      const float* ap = (const float*)&av;
      const float* bp = (const float*)&bv;
#pragma unroll
      for (int i = 0; i < 4; ++i)
#pragma unroll
        for (int j = 0; j < 4; ++j) acc[i][j] += ap[i] * bp[j];
    }
    __syncthreads();
  }
#pragma unroll
  for (int i = 0; i < 4; ++i) {
    int row = m0 + ty * 4 + i;
    alignas(8) f16 ov[4];
#pragma unroll
    for (int j = 0; j < 4; ++j) ov[j] = (f16)(acc[i][j] + bcol[j]);
    *(uint2*)(C + (size_t)row * 1024 + n0 + tx * 4) = *(const uint2*)ov;
  }
}

// ---------------- recurrent scan: one workgroup per batch element ----------------
// 512 threads; thread t owns gate columns t (i/f) and t+512 (g/o).
// U in fp8: 19/32 k-chunks resident in LDS, 13/32 streamed from per-XCD L2.
// h kept in LDS as f32, broadcast-read as float4 (wave-uniform = conflict-free).
// R6-proven structure (VGPR 36, zero scratch): two branch-free loops, unroll 4.
// Do NOT register-host the streamed chunks (R7: allocator caps at 128 VGPR for
// 512-thread blocks and spills ~107 dwords/thread -> 2x regression).
__global__ __launch_bounds__(512) void lstm_scan_f8(
    const uint2* __restrict__ Wall,  // [32][1024] fp8 chunks, layer-specific
    const f16* __restrict__ xz,      // [64][1024][1024]
    f16* __restrict__ hseq) {        // [64][1024][256]
  extern __shared__ char smem[];
  uint2* wlds = (uint2*)smem;                               // 155648 B
  float* hstore = (float*)(smem + QLDS * 1024 * 8);         // 1024 B
  float* arr = (float*)(smem + QLDS * 1024 * 8 + 1024);     // 4096 B
  float* red = (float*)(smem + QLDS * 1024 * 8 + 1024 + 4096);  // 64 B

  const int bid = blockIdx.x;
  const int t = threadIdx.x;
  const bool lowhalf = (t < 256);
  const uint2* Wt = Wall + QLDS * 1024;   // streamed tail chunks
  const float4* hst4 = (const float4*)hstore;

  // one-time copy of the LDS-resident W slice (from L2/HBM)
  for (int i = t; i < QLDS * 1024; i += 512) wlds[i] = Wall[i];
  if (lowhalf) hstore[t] = 0.f;
  float creg = 0.f;
  __syncthreads();

#pragma unroll 1
  for (int step = 0; step < TSTEPS; ++step) {
    const f16* xzrow = xz + ((size_t)bid * TSTEPS + step) * 1024;
    float xza = (float)xzrow[t];
    float xzb = (float)xzrow[t + 512];

    f32x2 aA0{0.f, 0.f}, aA1{0.f, 0.f}, aB0{0.f, 0.f}, aB1{0.f, 0.f};
#pragma unroll 4
    for (int q = 0; q < QLDS; ++q) {      // LDS-resident chunks
      uint2 wa = wlds[q * 1024 + t];
      uint2 wb = wlds[q * 1024 + t + 512];
      float4 h0 = hst4[2 * q];            // h[8q .. 8q+3] (broadcast)
      float4 h1 = hst4[2 * q + 1];        // h[8q+4 .. 8q+7]
      fp8x4_mac2(wa.x, h0, aA0, aA1);
      fp8x4_mac2(wa.y, h1, aA0, aA1);
      fp8x4_mac2(wb.x, h0, aB0, aB1);
      fp8x4_mac2(wb.y, h1, aB0, aB1);
    }
#pragma unroll 4
    for (int q = 0; q < QSTR; ++q) {      // streamed chunks (L2)
      uint2 wa = Wt[q * 1024 + t];
      uint2 wb = Wt[q * 1024 + t + 512];
      float4 h0 = hst4[2 * (QLDS + q)];
      float4 h1 = hst4[2 * (QLDS + q) + 1];
      fp8x4_mac2(wa.x, h0, aA0, aA1);
      fp8x4_mac2(wa.y, h1, aA0, aA1);
      fp8x4_mac2(wb.x, h0, aB0, aB1);
      fp8x4_mac2(wb.y, h1, aB0, aB1);
    }
    float za = xza + aA0.x + aA0.y + aA1.x + aA1.y;  // col t: i/f
    float zb = xzb + aB0.x + aB0.y + aB1.x + aB1.y;  // col t+512: g/o

    float sa = sigmf(za);
    float ab = lowhalf ? __expf(zb) : sigmf(zb);
    arr[t] = sa;
    arr[t + 512] = ab;

    if (lowhalf) {                    // g-gate exp sum
      float gs = wave_sum64(ab);
      if ((t & 63) == 0) red[t >> 6] = gs;
    }
    __syncthreads();

    float ec = 0.f;
    if (lowhalf) {
      float gsum = red[0] + red[1] + red[2] + red[3];
      float smg = ab / gsum;          // own g column is k=t
      creg = arr[256 + t] * creg + sa * smg;   // sig(f)*c + sig(i)*softmax(g)
      ec = __expf(creg);
      float cs = wave_sum64(ec);
      if ((t & 63) == 0) red[8 + (t >> 6)] = cs;
    }
    __syncthreads();

    if (lowhalf) {
      float csum = red[8] + red[9] + red[10] + red[11];
      float hv = arr[768 + t] * (ec / csum);   // sig(o)*softmax(c)
      hstore[t] = hv;
      hseq[((size_t)bid * TSTEPS + step) * NH + t] = (f16)hv;
    }
    __syncthreads();
  }
}

// ---------------- head: dense 256->100->40->2 + softmax ----------------
__global__ __launch_bounds__(128) void head_k(
    const f16* __restrict__ hseq,
    const float* __restrict__ d1w, const float* __restrict__ d1b,
    const float* __restrict__ d2w, const float* __restrict__ d2b,
    const float* __restrict__ d3w, const float* __restrict__ d3b,
    float* __restrict__ out) {
  __shared__ float hl[256], o1[100], o2[40];
  int b = blockIdx.x, t = threadIdx.x;
  const f16* hrow = hseq + ((size_t)b * TSTEPS + (TSTEPS - 1)) * NH;
  for (int i = t; i < 256; i += 128) hl[i] = (float)hrow[i];
  __syncthreads();
  if (t < 100) {
    float acc = d1b[t];
    for (int k = 0; k < 256; ++k) acc += hl[k] * d1w[k * 100 + t];
    o1[t] = fmaxf(acc, 0.f);
  }
  __syncthreads();
  if (t < 40) {
    float acc = d2b[t];
    for (int k = 0; k < 100; ++k) acc += o1[k] * d2w[k * 40 + t];
    o2[t] = fmaxf(acc, 0.f);
  }
  __syncthreads();
  if (t == 0) {
    float a0 = d3b[0], a1 = d3b[1];
    for (int k = 0; k < 40; ++k) {
      a0 += o2[k] * d3w[k * 2];
      a1 += o2[k] * d3w[k * 2 + 1];
    }
    float m = fmaxf(a0, a1);
    float e0 = __expf(a0 - m), e1 = __expf(a1 - m);
    float s = e0 + e1;
    out[b * 2] = e0 / s;
    out[b * 2 + 1] = e1 / s;
  }
}

extern "C" void kernel_launch(void* const* d_in, const int* in_sizes, int n_in,
                              void* d_out, int out_size, void* d_ws, size_t ws_size,
                              hipStream_t stream) {
  const float* x = (const float*)d_in[0];
  const float* pe_w1 = (const float*)d_in[1];
  const float* pe_b1 = (const float*)d_in[2];
  const float* pe_w2 = (const float*)d_in[3];
  const float* pe_b2 = (const float*)d_in[4];
  const float* te_w1 = (const float*)d_in[5];
  const float* te_b1 = (const float*)d_in[6];
  const float* te_w2 = (const float*)d_in[7];
  const float* te_b2 = (const float*)d_in[8];
  const float* W1 = (const float*)d_in[9];
  const float* U1 = (const float*)d_in[10];
  const float* bl1 = (const float*)d_in[11];
  const float* W2 = (const float*)d_in[12];
  const float* U2m = (const float*)d_in[13];
  const float* bl2 = (const float*)d_in[14];
  const float* W3 = (const float*)d_in[15];
  const float* U3 = (const float*)d_in[16];
  const float* bl3 = (const float*)d_in[17];
  const float* d1w = (const float*)d_in[18];
  const float* d1b = (const float*)d_in[19];
  const float* d2w = (const float*)d_in[20];
  const float* d2b = (const float*)d_in[21];
  const float* d3w = (const float*)d_in[22];
  const float* d3b = (const float*)d_in[23];
  float* out = (float*)d_out;

  char* ws = (char*)d_ws;
  float* feat = (float*)(ws + OFF_FEAT);
  f16* xzbuf = (f16*)(ws + OFF_XZ);
  f16* hseq = (f16*)(ws + OFF_H);
  uint2* upk = (uint2*)(ws + OFF_UPK);   // 3 layers x 32768 uint2

  hipFuncSetAttribute((const void*)lstm_scan_f8,
                      hipFuncAttributeMaxDynamicSharedMemorySize, SMEM_SCAN8);

  const float* Us[3] = {U1, U2m, U3};
  for (int l = 0; l < 3; ++l)
    cvt_u_fp8<<<128, 256, 0, stream>>>(Us[l], upk + (size_t)l * 32768);

  embed_feat<<<256, 256, 0, stream>>>(x, pe_w1, pe_b1, pe_w2, pe_b2,
                                      te_w1, te_b1, te_w2, te_b2, feat);
  gemm_feat<<<dim3(1024, 4), 256, 0, stream>>>(feat, W1, bl1, xzbuf);
  lstm_scan_f8<<<64, 512, SMEM_SCAN8, stream>>>(upk, xzbuf, hseq);

  gemm_h<<<dim3(1024, 16), 256, 0, stream>>>(hseq, W2, bl2, xzbuf);
  lstm_scan_f8<<<64, 512, SMEM_SCAN8, stream>>>(upk + 32768, xzbuf, hseq);

  gemm_h<<<dim3(1024, 16), 256, 0, stream>>>(hseq, W3, bl3, xzbuf);
  lstm_scan_f8<<<64, 512, SMEM_SCAN8, stream>>>(upk + 2 * 32768, xzbuf, hseq);

  head_k<<<64, 128, 0, stream>>>(hseq, d1w, d1b, d2w, d2b, d3w, d3b, out);
}